// Round 8
// baseline (608.095 us; speedup 1.0000x reference)
//
#include <hip/hip_runtime.h>
#include <stdint.h>
#include <stddef.h>

// ---------------------------------------------------------------------------
// cseft reassociated, W1 folded into U (R6 dataflow — confirmed best: R7's
// qb-variant regressed). ONE plain kernel, 5 phases, software grid barriers
// WITH EXPLICIT CACHE PROTOCOL:
//   R5 diagnosis: recorded absmax was the PASSING value; failure fired at the
//   later replay-consistency assert => run-1 correct (cold L2 miss -> fresh
//   fetch), replays wrong (consumer-XCD L2 warm with workspace POISON ->
//   stale hits). Plain __threadfence did not writeback/invalidate across
//   XCD L2s. Fix = kernel-boundary semantics done manually:
//     release: s_waitcnt vmcnt(0) ; buffer_wbl2 sc0 sc1 ; s_waitcnt vmcnt(0)
//     acquire: buffer_inv sc0 sc1 ; s_waitcnt vmcnt(0)
//   (the gfx94x cross-device flag protocol used by RCCL/MSCCLPP).
// Phases (all geometry identical to the verified R6 129.4us kernels):
//   P0 prep: xb=bf16(x), yb=bf16(y), w1b=bf16(W1), w23t=bf16([W2|W3]^T)
//   P1 kvt[2048,4096] = w23t @ yb^T          (512 tiles, XCD-swizzled)
//   P2 Ut (s,h) = cw[h]*sc * V_s @ K_s^T     (128 tiles, K=256)
//   P3 M[2048,512] = Ut @ W1                 (64 tiles,  K=1024)
//   P4 out[4096,2048] = xb @ M^T             (512 tiles, K=512, XCD-swizzled)
// Co-residency (required): 512 blocks = exactly 2/CU; LDS 64KB -> 2/CU cap;
// __launch_bounds__(256,2) caps VGPR<=256 -> 8 waves/CU <= 32. Bounded spin
// (~1.8s) exits visibly on violation instead of hanging.
// gemm_tile: R6-verified BK=64, dbuf 2x32KB, 1 barrier/step, T2 both-sides
// XOR swizzle (linear LDS dest + pre-swizzled global source + XOR'd ds_read).
// ---------------------------------------------------------------------------

typedef short short8 __attribute__((ext_vector_type(8)));
typedef float f32x4 __attribute__((ext_vector_type(4)));

#define AS1 __attribute__((address_space(1)))
#define AS3 __attribute__((address_space(3)))

__device__ __forceinline__ void gl_lds16(const void* g, void* l) {
    __builtin_amdgcn_global_load_lds((AS1 void*)(uintptr_t)g, (AS3 void*)l, 16, 0, 0);
}

__device__ __forceinline__ short f2bf(float f) {
    union { float f; unsigned u; } v; v.f = f;
    unsigned r = v.u + 0x7FFFu + ((v.u >> 16) & 1u);
    return (short)(r >> 16);
}

// --- software grid barrier with explicit cross-XCD cache protocol ----------
__device__ __forceinline__ void gbar(unsigned* cnt, unsigned target) {
    // RELEASE: drain my stores, write back dirty L2 so other XCDs see them
    asm volatile("s_waitcnt vmcnt(0) lgkmcnt(0)" ::: "memory");
    asm volatile("buffer_wbl2 sc0 sc1" ::: "memory");
    asm volatile("s_waitcnt vmcnt(0)" ::: "memory");
    __syncthreads();
    if (threadIdx.x == 0) {
        __hip_atomic_fetch_add(cnt, 1u, __ATOMIC_ACQ_REL,
                               __HIP_MEMORY_SCOPE_AGENT);
        unsigned tries = 0;
        while (__hip_atomic_load(cnt, __ATOMIC_ACQUIRE,
                                 __HIP_MEMORY_SCOPE_AGENT) < target &&
               ++tries < (1u << 22))
            __builtin_amdgcn_s_sleep(16);
    }
    __syncthreads();
    // ACQUIRE: drop stale (poison-warm) L1/L2 lines before reading
    asm volatile("buffer_inv sc0 sc1" ::: "memory");
    asm volatile("s_waitcnt vmcnt(0)" ::: "memory");
    __syncthreads();
}

// --- prep unit: u<2048 x/y->bf16; 2048..3071 W2/W3 transpose; >=3072 W1 cvt.
__device__ __forceinline__
void prep_unit(int u, int tid, const float* __restrict__ x,
               const float* __restrict__ y, const float* __restrict__ W1,
               const float* __restrict__ W2, const float* __restrict__ W3,
               short* __restrict__ xb, short* __restrict__ yb,
               short* __restrict__ w1b, short* __restrict__ w23t,
               char* smem) {
    if (u < 2048) {
        const float* in = (u < 1024) ? x : y;
        short* o = (u < 1024) ? xb : yb;
        const int i = (u & 1023) * 256 + tid;
        const float4* p = (const float4*)in + (size_t)i * 2;
        float4 a = p[0], c4 = p[1];
        short8 s8;
        s8[0] = f2bf(a.x);  s8[1] = f2bf(a.y);
        s8[2] = f2bf(a.z);  s8[3] = f2bf(a.w);
        s8[4] = f2bf(c4.x); s8[5] = f2bf(c4.y);
        s8[6] = f2bf(c4.z); s8[7] = f2bf(c4.w);
        *((short8*)o + i) = s8;
        return;
    }
    if (u >= 3072) {
        const int i = (u - 3072) * 256 + tid;
        const float4* p = (const float4*)W1 + (size_t)i * 2;
        float4 a = p[0], c4 = p[1];
        short8 s8;
        s8[0] = f2bf(a.x);  s8[1] = f2bf(a.y);
        s8[2] = f2bf(a.z);  s8[3] = f2bf(a.w);
        s8[4] = f2bf(c4.x); s8[5] = f2bf(c4.y);
        s8[6] = f2bf(c4.z); s8[7] = f2bf(c4.w);
        *((short8*)w1b + i) = s8;
        return;
    }
    float (*t)[33] = (float(*)[33])smem;         // 32x33 floats
    const int u2 = u - 2048;                     // 0..1023
    const int z = u2 >> 9;                       // 0: W2, 1: W3
    const float* W = z ? W3 : W2;
    short* Wt = w23t + (size_t)z * 1024 * 512;
    const int u3 = u2 & 511;
    const int bx = (u3 & 31) * 32, by = (u3 >> 5) * 32;
    const int tx = tid & 31, ty = tid >> 5;
    __syncthreads();   // protect t[][] from previous unit in this block
    #pragma unroll
    for (int j = 0; j < 4; ++j)
        t[ty + j * 8][tx] = W[(size_t)(by + ty + j * 8) * 1024 + bx + tx];
    __syncthreads();
    #pragma unroll
    for (int j = 0; j < 4; ++j)
        Wt[(size_t)(bx + ty + j * 8) * 512 + by + tx] = f2bf(t[tx][ty + j * 8]);
}

// --- generic MFMA tile (R6-verified): C[128x128] = A[.,K] * Bt[.,K]^T ------
// 4 waves 2x2; OUTMODE: 0 = f32 store, 1 = bf16 store, 2 = bf16*scale.
// BK=64, dbuf 2x32KB, 1 __syncthreads per step, XOR-swizzled LDS (T2).
template <int OUTMODE>
__device__ __forceinline__
void gemm_tile(const short* __restrict__ A, int lda,
               const short* __restrict__ Bt, int ldb,
               void* __restrict__ Cout, int ldc, int K,
               int bx, int by, float scale, char* smem) {
    const int tid = threadIdx.x;
    const int wave = tid >> 6, lane = tid & 63;
    const int quad = lane >> 4, ml = lane & 15;
    const int m0 = by * 128, n0 = bx * 128;
    const int wm0 = (wave >> 1) * 64, wn0 = (wave & 1) * 64;
    const int rl = lane >> 3;            // row within an 8-row group (0..7)
    const int ch = lane & 7;             // 16B chunk within 128B row (0..7)
    const int sch = ch ^ rl;             // source-swizzled chunk (involution)

    f32x4 acc[4][4];
    #pragma unroll
    for (int i = 0; i < 4; ++i)
        #pragma unroll
        for (int j = 0; j < 4; ++j) {
            acc[i][j][0] = 0.f; acc[i][j][1] = 0.f;
            acc[i][j][2] = 0.f; acc[i][j][3] = 0.f;
        }

    auto STAGE = [&](char* sbuf, int kt) {
        #pragma unroll
        for (int j = 0; j < 4; ++j) {
            const int r = (wave * 4 + j) * 8 + rl;
            gl_lds16(A + (size_t)(m0 + r) * lda + kt + sch * 8,
                     sbuf + (wave * 4 + j) * 1024 + lane * 16);
        }
        #pragma unroll
        for (int j = 0; j < 4; ++j) {
            const int r = (wave * 4 + j) * 8 + rl;
            gl_lds16(Bt + (size_t)(n0 + r) * ldb + kt + sch * 8,
                     sbuf + 16384 + (wave * 4 + j) * 1024 + lane * 16);
        }
    };

    const int nt = K >> 6;               // >= 4 at every call site
    STAGE(smem, 0);
    __syncthreads();                     // drain vmcnt(0): buf0 ready

    for (int t = 0; t < nt; ++t) {
        char* sbuf = smem + (t & 1) * 32768;
        if (t + 1 < nt)
            STAGE(smem + ((t + 1) & 1) * 32768, (t + 1) * 64);  // prefetch

        const short* sA = (const short*)sbuf;
        const short* sB = (const short*)(sbuf + 16384);
        #pragma unroll
        for (int kk = 0; kk < 2; ++kk) {
            short8 af[4], bfr[4];
            #pragma unroll
            for (int mt = 0; mt < 4; ++mt) {
                const int row = wm0 + mt * 16 + ml;
                af[mt] = *(const short8*)(sA + row * 64 +
                                          (((kk << 2) + quad) ^ (row & 7)) * 8);
            }
            #pragma unroll
            for (int nt2 = 0; nt2 < 4; ++nt2) {
                const int row = wn0 + nt2 * 16 + ml;
                bfr[nt2] = *(const short8*)(sB + row * 64 +
                                            (((kk << 2) + quad) ^ (row & 7)) * 8);
            }
            #pragma unroll
            for (int mt = 0; mt < 4; ++mt)
                #pragma unroll
                for (int nt2 = 0; nt2 < 4; ++nt2)
                    acc[mt][nt2] = __builtin_amdgcn_mfma_f32_16x16x32_bf16(
                        af[mt], bfr[nt2], acc[mt][nt2], 0, 0, 0);
        }
        __syncthreads();  // next buf ready; all waves done reading sbuf
    }

    // C/D layout: col = lane&15, row = quad*4 + reg
    #pragma unroll
    for (int mt = 0; mt < 4; ++mt)
        #pragma unroll
        for (int nt2 = 0; nt2 < 4; ++nt2) {
            const int col = n0 + wn0 + nt2 * 16 + ml;
            #pragma unroll
            for (int r = 0; r < 4; ++r) {
                const int row = m0 + wm0 + mt * 16 + quad * 4 + r;
                float v = acc[mt][nt2][r];
                if (OUTMODE == 2) v *= scale;
                if (OUTMODE == 0)
                    ((float*)Cout)[(size_t)row * ldc + col] = v;
                else
                    ((short*)Cout)[(size_t)row * ldc + col] = f2bf(v);
            }
        }
}

// --- fused kernel: 512 blocks x 256 threads, sw grid barriers --------------
__global__ __launch_bounds__(256, 2)
void fused(const float* __restrict__ x, const float* __restrict__ y,
           const float* __restrict__ W1, const float* __restrict__ W2,
           const float* __restrict__ W3, const float* __restrict__ cw,
           float* __restrict__ out, short* __restrict__ xb,
           short* __restrict__ yb, short* __restrict__ w23t,
           short* __restrict__ w1b, short* __restrict__ kvt,
           short* __restrict__ Ut, short* __restrict__ M,
           unsigned* __restrict__ bar) {
    __shared__ char smem[65536];
    const int b = blockIdx.x, tid = threadIdx.x;

    // P0: prep — grid-stride over 3328 units
    for (int u = b; u < 3328; u += 512)
        prep_unit(u, tid, x, y, W1, W2, W3, xb, yb, w1b, w23t, smem);
    gbar(bar, 512);

    // P1: kvt[2048,4096] = w23t @ yb^T (512 tiles, XCD-swizzled)
    {
        const int b2 = (b & 7) * 64 + (b >> 3);
        gemm_tile<1>(w23t, 512, yb, 512, kvt, 4096, 512,
                     b2 & 31, b2 >> 5, 1.f, smem);
    }
    gbar(bar, 1024);

    // P2: build_u — 128 tiles (s,h), K=256
    if (b < 128) {
        const int s = b & 15, h = b >> 4;
        const float scale = cw[h] * (0.08838834764831845f / 256.0f);
        gemm_tile<2>(kvt + (size_t)(1024 + h * 128) * 4096 + s * 256, 4096,
                     kvt + (size_t)(h * 128) * 4096 + s * 256, 4096,
                     Ut + (size_t)(s * 128) * 1024 + h * 128, 1024, 256,
                     0, 0, scale, smem);
    }
    gbar(bar, 1536);

    // P3: build_m — M[2048,512] = Ut @ W1, 64 tiles, K=1024
    if (b < 64)
        gemm_tile<1>(Ut, 1024, w1b, 1024, M, 512, 1024,
                     b & 3, b >> 2, 1.f, smem);
    gbar(bar, 2048);

    // P4: out[4096,2048] = xb @ M^T (512 tiles, K=512, XCD-swizzled)
    {
        const int b2 = (b & 7) * 64 + (b >> 3);
        gemm_tile<0>(xb, 512, M, 512, out, 2048, 512,
                     b2 & 15, b2 >> 4, 1.f, smem);
    }
}

extern "C" void kernel_launch(void* const* d_in, const int* in_sizes, int n_in,
                              void* d_out, int out_size, void* d_ws, size_t ws_size,
                              hipStream_t stream) {
    const float* x  = (const float*)d_in[0];  // [4096, 512]
    const float* y  = (const float*)d_in[1];  // [4096, 512]
    const float* W1 = (const float*)d_in[2];  // [512, 1024]
    const float* W2 = (const float*)d_in[3];
    const float* W3 = (const float*)d_in[4];
    const float* cw = (const float*)d_in[5];  // [8]
    float* out = (float*)d_out;               // [4096, 16, 128]

    short* xb   = (short*)d_ws;                       // 4096*512
    short* yb   = xb   + (size_t)4096 * 512;          // 4096*512
    short* w23t = yb   + (size_t)4096 * 512;          // 2048*512 (transposed)
    short* w1b  = w23t + (size_t)2048 * 512;          // 512*1024 (row-major)
    short* kvt  = w1b  + (size_t)512 * 1024;          // 2048*4096
    short* Ut   = kvt  + (size_t)2048 * 4096;         // 2048*1024
    short* M    = Ut   + (size_t)2048 * 1024;         // 2048*512
    uintptr_t be = (uintptr_t)(M + (size_t)2048 * 512);
    unsigned* bar = (unsigned*)((be + 255) & ~(uintptr_t)255);

    hipMemsetAsync(bar, 0, 64, stream);   // graph-capturable, replayed
    fused<<<512, 256, 0, stream>>>(x, y, W1, W2, W3, cw, out,
                                   xb, yb, w23t, w1b, kvt, Ut, M, bar);
}

// Round 9
// 278.669 us; speedup vs baseline: 2.1821x; 2.1821x over previous
//
#include <hip/hip_runtime.h>
#include <stdint.h>
#include <stddef.h>

// ---------------------------------------------------------------------------
// cseft reassociated, W1 folded into U (R6 dataflow). ONE plain kernel,
// 5 phases, software grid barriers with explicit cross-XCD cache protocol.
//
// R8 post-mortem: this exact kernel PASSED (incl. replays) but ran 530us,
// MfmaUtil 1.5%, HBM 3% -> pure latency poisoning. Cause: the spin used
// __ATOMIC_ACQUIRE at agent scope, which emits buffer_inv PER POLL; 512
// spinning lanes continuously invalidated every XCD's L1/L2 while other
// blocks computed (every load -> ~900cy). Also all 2048 waves issued
// wbl2/inv redundantly. Fix (this round): RELAXED polls (no cache op),
// cache ops issued ONCE by wave 0 of each block (block is on one CU: its
// buffer_inv covers that CU's L1 + the XCD's L2). Protocol flags and
// ordering unchanged from the proven-correct R8 version.
//
// Phases (geometry identical to verified R6 129.4us kernels):
//   P0 prep: xb=bf16(x), yb=bf16(y), w1b=bf16(W1), w23t=bf16([W2|W3]^T)
//   P1 kvt[2048,4096] = w23t @ yb^T          (512 tiles, XCD-swizzled)
//   P2 Ut (s,h) = cw[h]*sc * V_s @ K_s^T     (128 tiles, K=256)
//   P3 M[2048,512] = Ut @ W1                 (64 tiles,  K=1024)
//   P4 out[4096,2048] = xb @ M^T             (512 tiles, K=512, XCD-swizzled)
// Co-residency: 512 blocks = 2/CU exactly (LDS 64KB caps 2/CU;
// __launch_bounds__(256,2) caps VGPR). Bounded spin exits visibly.
// gemm_tile: R6-verified BK=64, dbuf 2x32KB, 1 barrier/step, T2 both-sides
// XOR swizzle. Fallback if this round fails: R6 5-launch kernel (129.4us).
// ---------------------------------------------------------------------------

typedef short short8 __attribute__((ext_vector_type(8)));
typedef float f32x4 __attribute__((ext_vector_type(4)));

#define AS1 __attribute__((address_space(1)))
#define AS3 __attribute__((address_space(3)))

__device__ __forceinline__ void gl_lds16(const void* g, void* l) {
    __builtin_amdgcn_global_load_lds((AS1 void*)(uintptr_t)g, (AS3 void*)l, 16, 0, 0);
}

__device__ __forceinline__ short f2bf(float f) {
    union { float f; unsigned u; } v; v.f = f;
    unsigned r = v.u + 0x7FFFu + ((v.u >> 16) & 1u);
    return (short)(r >> 16);
}

// --- software grid barrier, cross-XCD safe, relaxed-poll -------------------
__device__ __forceinline__ void gbar(unsigned* cnt, unsigned target) {
    // 1) every wave drains its own stores into L2
    asm volatile("s_waitcnt vmcnt(0) lgkmcnt(0)" ::: "memory");
    __syncthreads();
    // 2) ONE wave writes back this XCD's dirty L2 to the memory-side cache
    if (threadIdx.x < 64) {
        asm volatile("buffer_wbl2 sc0 sc1" ::: "memory");
        asm volatile("s_waitcnt vmcnt(0)" ::: "memory");
    }
    __syncthreads();
    // 3) arrive + RELAXED spin (no per-poll cache op — R8's 124us/barrier bug)
    if (threadIdx.x == 0) {
        __hip_atomic_fetch_add(cnt, 1u, __ATOMIC_RELAXED,
                               __HIP_MEMORY_SCOPE_AGENT);
        unsigned tries = 0;
        while (__hip_atomic_load(cnt, __ATOMIC_RELAXED,
                                 __HIP_MEMORY_SCOPE_AGENT) < target &&
               ++tries < (1u << 21))
            __builtin_amdgcn_s_sleep(2);
    }
    __syncthreads();
    // 4) ONE wave invalidates this CU's L1 + this XCD's L2 (drop stale lines)
    if (threadIdx.x < 64) {
        asm volatile("buffer_inv sc0 sc1" ::: "memory");
        asm volatile("s_waitcnt vmcnt(0)" ::: "memory");
    }
    __syncthreads();
}

// --- prep unit: u<2048 x/y->bf16; 2048..3071 W2/W3 transpose; >=3072 W1 cvt.
__device__ __forceinline__
void prep_unit(int u, int tid, const float* __restrict__ x,
               const float* __restrict__ y, const float* __restrict__ W1,
               const float* __restrict__ W2, const float* __restrict__ W3,
               short* __restrict__ xb, short* __restrict__ yb,
               short* __restrict__ w1b, short* __restrict__ w23t,
               char* smem) {
    if (u < 2048) {
        const float* in = (u < 1024) ? x : y;
        short* o = (u < 1024) ? xb : yb;
        const int i = (u & 1023) * 256 + tid;
        const float4* p = (const float4*)in + (size_t)i * 2;
        float4 a = p[0], c4 = p[1];
        short8 s8;
        s8[0] = f2bf(a.x);  s8[1] = f2bf(a.y);
        s8[2] = f2bf(a.z);  s8[3] = f2bf(a.w);
        s8[4] = f2bf(c4.x); s8[5] = f2bf(c4.y);
        s8[6] = f2bf(c4.z); s8[7] = f2bf(c4.w);
        *((short8*)o + i) = s8;
        return;
    }
    if (u >= 3072) {
        const int i = (u - 3072) * 256 + tid;
        const float4* p = (const float4*)W1 + (size_t)i * 2;
        float4 a = p[0], c4 = p[1];
        short8 s8;
        s8[0] = f2bf(a.x);  s8[1] = f2bf(a.y);
        s8[2] = f2bf(a.z);  s8[3] = f2bf(a.w);
        s8[4] = f2bf(c4.x); s8[5] = f2bf(c4.y);
        s8[6] = f2bf(c4.z); s8[7] = f2bf(c4.w);
        *((short8*)w1b + i) = s8;
        return;
    }
    float (*t)[33] = (float(*)[33])smem;         // 32x33 floats
    const int u2 = u - 2048;                     // 0..1023
    const int z = u2 >> 9;                       // 0: W2, 1: W3
    const float* W = z ? W3 : W2;
    short* Wt = w23t + (size_t)z * 1024 * 512;
    const int u3 = u2 & 511;
    const int bx = (u3 & 31) * 32, by = (u3 >> 5) * 32;
    const int tx = tid & 31, ty = tid >> 5;
    __syncthreads();   // protect t[][] from previous unit in this block
    #pragma unroll
    for (int j = 0; j < 4; ++j)
        t[ty + j * 8][tx] = W[(size_t)(by + ty + j * 8) * 1024 + bx + tx];
    __syncthreads();
    #pragma unroll
    for (int j = 0; j < 4; ++j)
        Wt[(size_t)(bx + ty + j * 8) * 512 + by + tx] = f2bf(t[tx][ty + j * 8]);
}

// --- generic MFMA tile (R6-verified): C[128x128] = A[.,K] * Bt[.,K]^T ------
// 4 waves 2x2; OUTMODE: 0 = f32 store, 1 = bf16 store, 2 = bf16*scale.
// BK=64, dbuf 2x32KB, 1 __syncthreads per step, XOR-swizzled LDS (T2).
template <int OUTMODE>
__device__ __forceinline__
void gemm_tile(const short* __restrict__ A, int lda,
               const short* __restrict__ Bt, int ldb,
               void* __restrict__ Cout, int ldc, int K,
               int bx, int by, float scale, char* smem) {
    const int tid = threadIdx.x;
    const int wave = tid >> 6, lane = tid & 63;
    const int quad = lane >> 4, ml = lane & 15;
    const int m0 = by * 128, n0 = bx * 128;
    const int wm0 = (wave >> 1) * 64, wn0 = (wave & 1) * 64;
    const int rl = lane >> 3;            // row within an 8-row group (0..7)
    const int ch = lane & 7;             // 16B chunk within 128B row (0..7)
    const int sch = ch ^ rl;             // source-swizzled chunk (involution)

    f32x4 acc[4][4];
    #pragma unroll
    for (int i = 0; i < 4; ++i)
        #pragma unroll
        for (int j = 0; j < 4; ++j) {
            acc[i][j][0] = 0.f; acc[i][j][1] = 0.f;
            acc[i][j][2] = 0.f; acc[i][j][3] = 0.f;
        }

    auto STAGE = [&](char* sbuf, int kt) {
        #pragma unroll
        for (int j = 0; j < 4; ++j) {
            const int r = (wave * 4 + j) * 8 + rl;
            gl_lds16(A + (size_t)(m0 + r) * lda + kt + sch * 8,
                     sbuf + (wave * 4 + j) * 1024 + lane * 16);
        }
        #pragma unroll
        for (int j = 0; j < 4; ++j) {
            const int r = (wave * 4 + j) * 8 + rl;
            gl_lds16(Bt + (size_t)(n0 + r) * ldb + kt + sch * 8,
                     sbuf + 16384 + (wave * 4 + j) * 1024 + lane * 16);
        }
    };

    const int nt = K >> 6;               // >= 4 at every call site
    STAGE(smem, 0);
    __syncthreads();                     // drain vmcnt(0): buf0 ready

    for (int t = 0; t < nt; ++t) {
        char* sbuf = smem + (t & 1) * 32768;
        if (t + 1 < nt)
            STAGE(smem + ((t + 1) & 1) * 32768, (t + 1) * 64);  // prefetch

        const short* sA = (const short*)sbuf;
        const short* sB = (const short*)(sbuf + 16384);
        #pragma unroll
        for (int kk = 0; kk < 2; ++kk) {
            short8 af[4], bfr[4];
            #pragma unroll
            for (int mt = 0; mt < 4; ++mt) {
                const int row = wm0 + mt * 16 + ml;
                af[mt] = *(const short8*)(sA + row * 64 +
                                          (((kk << 2) + quad) ^ (row & 7)) * 8);
            }
            #pragma unroll
            for (int nt2 = 0; nt2 < 4; ++nt2) {
                const int row = wn0 + nt2 * 16 + ml;
                bfr[nt2] = *(const short8*)(sB + row * 64 +
                                            (((kk << 2) + quad) ^ (row & 7)) * 8);
            }
            #pragma unroll
            for (int mt = 0; mt < 4; ++mt)
                #pragma unroll
                for (int nt2 = 0; nt2 < 4; ++nt2)
                    acc[mt][nt2] = __builtin_amdgcn_mfma_f32_16x16x32_bf16(
                        af[mt], bfr[nt2], acc[mt][nt2], 0, 0, 0);
        }
        __syncthreads();  // next buf ready; all waves done reading sbuf
    }

    // C/D layout: col = lane&15, row = quad*4 + reg
    #pragma unroll
    for (int mt = 0; mt < 4; ++mt)
        #pragma unroll
        for (int nt2 = 0; nt2 < 4; ++nt2) {
            const int col = n0 + wn0 + nt2 * 16 + ml;
            #pragma unroll
            for (int r = 0; r < 4; ++r) {
                const int row = m0 + wm0 + mt * 16 + quad * 4 + r;
                float v = acc[mt][nt2][r];
                if (OUTMODE == 2) v *= scale;
                if (OUTMODE == 0)
                    ((float*)Cout)[(size_t)row * ldc + col] = v;
                else
                    ((short*)Cout)[(size_t)row * ldc + col] = f2bf(v);
            }
        }
}

// --- fused kernel: 512 blocks x 256 threads, sw grid barriers --------------
__global__ __launch_bounds__(256, 2)
void fused(const float* __restrict__ x, const float* __restrict__ y,
           const float* __restrict__ W1, const float* __restrict__ W2,
           const float* __restrict__ W3, const float* __restrict__ cw,
           float* __restrict__ out, short* __restrict__ xb,
           short* __restrict__ yb, short* __restrict__ w23t,
           short* __restrict__ w1b, short* __restrict__ kvt,
           short* __restrict__ Ut, short* __restrict__ M,
           unsigned* __restrict__ bar) {
    __shared__ char smem[65536];
    const int b = blockIdx.x, tid = threadIdx.x;

    // P0: prep — grid-stride over 3328 units
    for (int u = b; u < 3328; u += 512)
        prep_unit(u, tid, x, y, W1, W2, W3, xb, yb, w1b, w23t, smem);
    gbar(bar, 512);

    // P1: kvt[2048,4096] = w23t @ yb^T (512 tiles, XCD-swizzled)
    {
        const int b2 = (b & 7) * 64 + (b >> 3);
        gemm_tile<1>(w23t, 512, yb, 512, kvt, 4096, 512,
                     b2 & 31, b2 >> 5, 1.f, smem);
    }
    gbar(bar, 1024);

    // P2: build_u — 128 tiles (s,h), K=256
    if (b < 128) {
        const int s = b & 15, h = b >> 4;
        const float scale = cw[h] * (0.08838834764831845f / 256.0f);
        gemm_tile<2>(kvt + (size_t)(1024 + h * 128) * 4096 + s * 256, 4096,
                     kvt + (size_t)(h * 128) * 4096 + s * 256, 4096,
                     Ut + (size_t)(s * 128) * 1024 + h * 128, 1024, 256,
                     0, 0, scale, smem);
    }
    gbar(bar, 1536);

    // P3: build_m — M[2048,512] = Ut @ W1, 64 tiles, K=1024
    if (b < 64)
        gemm_tile<1>(Ut, 1024, w1b, 1024, M, 512, 1024,
                     b & 3, b >> 2, 1.f, smem);
    gbar(bar, 2048);

    // P4: out[4096,2048] = xb @ M^T (512 tiles, K=512, XCD-swizzled)
    {
        const int b2 = (b & 7) * 64 + (b >> 3);
        gemm_tile<0>(xb, 512, M, 512, out, 2048, 512,
                     b2 & 15, b2 >> 4, 1.f, smem);
    }
}

extern "C" void kernel_launch(void* const* d_in, const int* in_sizes, int n_in,
                              void* d_out, int out_size, void* d_ws, size_t ws_size,
                              hipStream_t stream) {
    const float* x  = (const float*)d_in[0];  // [4096, 512]
    const float* y  = (const float*)d_in[1];  // [4096, 512]
    const float* W1 = (const float*)d_in[2];  // [512, 1024]
    const float* W2 = (const float*)d_in[3];
    const float* W3 = (const float*)d_in[4];
    const float* cw = (const float*)d_in[5];  // [8]
    float* out = (float*)d_out;               // [4096, 16, 128]

    short* xb   = (short*)d_ws;                       // 4096*512
    short* yb   = xb   + (size_t)4096 * 512;          // 4096*512
    short* w23t = yb   + (size_t)4096 * 512;          // 2048*512 (transposed)
    short* w1b  = w23t + (size_t)2048 * 512;          // 512*1024 (row-major)
    short* kvt  = w1b  + (size_t)512 * 1024;          // 2048*4096
    short* Ut   = kvt  + (size_t)2048 * 4096;         // 2048*1024
    short* M    = Ut   + (size_t)2048 * 1024;         // 2048*512
    uintptr_t be = (uintptr_t)(M + (size_t)2048 * 512);
    unsigned* bar = (unsigned*)((be + 255) & ~(uintptr_t)255);

    hipMemsetAsync(bar, 0, 64, stream);   // graph-capturable, replayed
    fused<<<512, 256, 0, stream>>>(x, y, W1, W2, W3, cw, out,
                                   xb, yb, w23t, w1b, kvt, Ut, M, bar);
}

// Round 10
// 156.178 us; speedup vs baseline: 3.8936x; 1.7843x over previous
//
#include <hip/hip_runtime.h>
#include <stdint.h>
#include <stddef.h>

// ---------------------------------------------------------------------------
// cseft reassociated, W1 folded into U. 5 launches (R6-verified skeleton):
//   1. prep:  w23t = bf16([W2|W3]^T) [2048,512]   (transpose only — all
//              straight fp32->bf16 conversions folded into consumers)
//   2. stage_kv: kvt[2048,4096] = w23t @ bf16(y)^T      (B reg-staged f32)
//   3. build_u:  Ut[s*128+d][h*128+dp] = cw[h]*sc * V_s @ K_s^T (K=256)
//   4. build_m:  M[2048,512] = Ut @ bf16(W1)^T-form     (B reg-staged f32)
//   5. gemm_out: out[4096,2048] = bf16(x) @ M^T         (A reg-staged f32)
// N=4096 K=512 H=8 Dh=128 nItem=256 nSet=16 hardcoded.
//
// gemm_tile: BK=64 dbuf 2x32KB, 1 __syncthreads/step, T2 both-sides XOR
// swizzle. NEW: template<F32A,F32B> reg-staged operand path (T14 split:
// issue f32 loads for t+1 BEFORE compute of t; cvt+ds_write AFTER compute,
// before the barrier) — preserves prefetch overlap. f2bf is the same RNE
// as before -> output bit-identical to R6 (absmax 0.0625).
//
// CLOSED ARCS (do not reopen):
// - Fusion: R3 coop launch never ran under graph capture; R5 sw-barrier
//   replay-diverged (stale per-XCD L2); R8 acquire-per-poll = 124us/barrier;
//   R9 relaxed+block-wise wbl2/inv = still 211us (buffer_inv wipes whole L2,
//   every phase refetches at latency). Kernel boundaries win.
// - R7 qb-dataflow (4 launches, K=1024 out): 132.2 vs R6 129.4. Reverted.
// Accounting: ~90us harness fill floor + ~10us gaps (4 x ~2.5) + phases.
// ---------------------------------------------------------------------------

typedef short short8 __attribute__((ext_vector_type(8)));
typedef float f32x4 __attribute__((ext_vector_type(4)));

#define AS1 __attribute__((address_space(1)))
#define AS3 __attribute__((address_space(3)))

__device__ __forceinline__ void gl_lds16(const void* g, void* l) {
    __builtin_amdgcn_global_load_lds((AS1 void*)(uintptr_t)g, (AS3 void*)l, 16, 0, 0);
}

__device__ __forceinline__ short f2bf(float f) {
    union { float f; unsigned u; } v; v.f = f;
    unsigned r = v.u + 0x7FFFu + ((v.u >> 16) & 1u);
    return (short)(r >> 16);
}

// --- prep: W2/W3 -> w23t transpose only. 1024 blocks x 256 thr. ------------
__global__ __launch_bounds__(256)
void prep(const float* __restrict__ W2, const float* __restrict__ W3,
          short* __restrict__ w23t) {
    const int b = blockIdx.x, tid = threadIdx.x;
    __shared__ float t[32][33];
    const int z = b >> 9;                        // 0: W2, 1: W3
    const float* W = z ? W3 : W2;
    short* Wt = w23t + (size_t)z * 1024 * 512;
    const int b3 = b & 511;
    const int bx = (b3 & 31) * 32, by = (b3 >> 5) * 32;
    const int tx = tid & 31, ty = tid >> 5;
    #pragma unroll
    for (int j = 0; j < 4; ++j)
        t[ty + j * 8][tx] = W[(size_t)(by + ty + j * 8) * 1024 + bx + tx];
    __syncthreads();
    #pragma unroll
    for (int j = 0; j < 4; ++j)
        Wt[(size_t)(bx + ty + j * 8) * 512 + by + tx] = f2bf(t[tx][ty + j * 8]);
}

// --- generic MFMA tile: C[128x128] = A[.,K] * Bt[.,K]^T --------------------
// 4 waves 2x2; OUTMODE: 0 = f32 store, 1 = bf16 store, 2 = bf16*scale.
// F32A/F32B: operand is fp32 in global; reg-stage (load->cvt->ds_write)
// instead of global_load_lds. Same LDS layout + XOR swizzle either way.
template <int OUTMODE, bool F32A, bool F32B>
__device__ __forceinline__
void gemm_tile(const void* __restrict__ A_, int lda,
               const void* __restrict__ Bt_, int ldb,
               void* __restrict__ Cout, int ldc, int K,
               int bx, int by, float scale, char* smem) {
    const short* A  = (const short*)A_;
    const float* Af = (const float*)A_;
    const short* Bt  = (const short*)Bt_;
    const float* Btf = (const float*)Bt_;

    const int tid = threadIdx.x;
    const int wave = tid >> 6, lane = tid & 63;
    const int quad = lane >> 4, ml = lane & 15;
    const int m0 = by * 128, n0 = bx * 128;
    const int wm0 = (wave >> 1) * 64, wn0 = (wave & 1) * 64;
    const int rl = lane >> 3;            // row within an 8-row group (0..7)
    const int ch = lane & 7;             // 16B chunk within 128B row (0..7)
    const int sch = ch ^ rl;             // source-swizzled chunk (involution)

    f32x4 acc[4][4];
    #pragma unroll
    for (int i = 0; i < 4; ++i)
        #pragma unroll
        for (int j = 0; j < 4; ++j) {
            acc[i][j][0] = 0.f; acc[i][j][1] = 0.f;
            acc[i][j][2] = 0.f; acc[i][j][3] = 0.f;
        }

    // bf16 operands: direct global->LDS (4 instrs, 8 rows x 128B each)
    auto STAGE_A_LDS = [&](char* sbuf, int kt) {
        #pragma unroll
        for (int j = 0; j < 4; ++j) {
            const int r = (wave * 4 + j) * 8 + rl;
            gl_lds16(A + (size_t)(m0 + r) * lda + kt + sch * 8,
                     sbuf + (wave * 4 + j) * 1024 + lane * 16);
        }
    };
    auto STAGE_B_LDS = [&](char* sbuf, int kt) {
        #pragma unroll
        for (int j = 0; j < 4; ++j) {
            const int r = (wave * 4 + j) * 8 + rl;
            gl_lds16(Bt + (size_t)(n0 + r) * ldb + kt + sch * 8,
                     sbuf + 16384 + (wave * 4 + j) * 1024 + lane * 16);
        }
    };
    // f32 operands: issue loads early (regs), cvt+ds_write late (T14 split)
    float4 ra[8], rb[8];
    auto ISSUE_A_F32 = [&](int kt) {
        #pragma unroll
        for (int j = 0; j < 4; ++j) {
            const float* p = Af + (size_t)(m0 + (wave * 4 + j) * 8 + rl) * lda
                              + kt + sch * 8;
            ra[j * 2]     = *(const float4*)p;
            ra[j * 2 + 1] = *(const float4*)(p + 4);
        }
    };
    auto ISSUE_B_F32 = [&](int kt) {
        #pragma unroll
        for (int j = 0; j < 4; ++j) {
            const float* p = Btf + (size_t)(n0 + (wave * 4 + j) * 8 + rl) * ldb
                               + kt + sch * 8;
            rb[j * 2]     = *(const float4*)p;
            rb[j * 2 + 1] = *(const float4*)(p + 4);
        }
    };
    auto WRITE_A_F32 = [&](char* sbuf) {
        #pragma unroll
        for (int j = 0; j < 4; ++j) {
            short8 s;
            s[0] = f2bf(ra[j*2].x);   s[1] = f2bf(ra[j*2].y);
            s[2] = f2bf(ra[j*2].z);   s[3] = f2bf(ra[j*2].w);
            s[4] = f2bf(ra[j*2+1].x); s[5] = f2bf(ra[j*2+1].y);
            s[6] = f2bf(ra[j*2+1].z); s[7] = f2bf(ra[j*2+1].w);
            *(short8*)(sbuf + (wave * 4 + j) * 1024 + lane * 16) = s;
        }
    };
    auto WRITE_B_F32 = [&](char* sbuf) {
        #pragma unroll
        for (int j = 0; j < 4; ++j) {
            short8 s;
            s[0] = f2bf(rb[j*2].x);   s[1] = f2bf(rb[j*2].y);
            s[2] = f2bf(rb[j*2].z);   s[3] = f2bf(rb[j*2].w);
            s[4] = f2bf(rb[j*2+1].x); s[5] = f2bf(rb[j*2+1].y);
            s[6] = f2bf(rb[j*2+1].z); s[7] = f2bf(rb[j*2+1].w);
            *(short8*)(sbuf + 16384 + (wave * 4 + j) * 1024 + lane * 16) = s;
        }
    };

    const int nt = K >> 6;               // >= 4 at every call site
    // prologue: fill buf0
    if constexpr (F32A) { ISSUE_A_F32(0); } else { STAGE_A_LDS(smem, 0); }
    if constexpr (F32B) { ISSUE_B_F32(0); } else { STAGE_B_LDS(smem, 0); }
    if constexpr (F32A) WRITE_A_F32(smem);
    if constexpr (F32B) WRITE_B_F32(smem);
    __syncthreads();                     // drains vmcnt+lgkmcnt: buf0 ready

    for (int t = 0; t < nt; ++t) {
        char* cur = smem + (t & 1) * 32768;
        char* nxt = smem + ((t + 1) & 1) * 32768;
        if (t + 1 < nt) {                // prefetch issue BEFORE compute
            if constexpr (F32A) { ISSUE_A_F32((t + 1) * 64); }
            else                { STAGE_A_LDS(nxt, (t + 1) * 64); }
            if constexpr (F32B) { ISSUE_B_F32((t + 1) * 64); }
            else                { STAGE_B_LDS(nxt, (t + 1) * 64); }
        }

        const short* sA = (const short*)cur;
        const short* sB = (const short*)(cur + 16384);
        #pragma unroll
        for (int kk = 0; kk < 2; ++kk) {
            short8 af[4], bfr[4];
            #pragma unroll
            for (int mt = 0; mt < 4; ++mt) {
                const int row = wm0 + mt * 16 + ml;
                af[mt] = *(const short8*)(sA + row * 64 +
                                          (((kk << 2) + quad) ^ (row & 7)) * 8);
            }
            #pragma unroll
            for (int nt2 = 0; nt2 < 4; ++nt2) {
                const int row = wn0 + nt2 * 16 + ml;
                bfr[nt2] = *(const short8*)(sB + row * 64 +
                                            (((kk << 2) + quad) ^ (row & 7)) * 8);
            }
            #pragma unroll
            for (int mt = 0; mt < 4; ++mt)
                #pragma unroll
                for (int nt2 = 0; nt2 < 4; ++nt2)
                    acc[mt][nt2] = __builtin_amdgcn_mfma_f32_16x16x32_bf16(
                        af[mt], bfr[nt2], acc[mt][nt2], 0, 0, 0);
        }

        if (t + 1 < nt) {                // cvt+write AFTER compute (T14)
            if constexpr (F32A) WRITE_A_F32(nxt);
            if constexpr (F32B) WRITE_B_F32(nxt);
        }
        __syncthreads();  // next buf ready; all waves done reading cur
    }

    // C/D layout: col = lane&15, row = quad*4 + reg
    #pragma unroll
    for (int mt = 0; mt < 4; ++mt)
        #pragma unroll
        for (int nt2 = 0; nt2 < 4; ++nt2) {
            const int col = n0 + wn0 + nt2 * 16 + ml;
            #pragma unroll
            for (int r = 0; r < 4; ++r) {
                const int row = m0 + wm0 + mt * 16 + quad * 4 + r;
                float v = acc[mt][nt2][r];
                if (OUTMODE == 2) v *= scale;
                if (OUTMODE == 0)
                    ((float*)Cout)[(size_t)row * ldc + col] = v;
                else
                    ((short*)Cout)[(size_t)row * ldc + col] = f2bf(v);
            }
        }
}

// stage_kv: kvt[2048,4096] = w23t @ bf16(y)^T. 512 blocks, XCD-swizzled.
__global__ __launch_bounds__(256)
void stage_kv(const float* __restrict__ y, const short* __restrict__ w23t,
              short* __restrict__ kvt) {
    __shared__ char smem[65536];
    const int b = (blockIdx.x & 7) * 64 + (blockIdx.x >> 3);
    gemm_tile<1, false, true>(w23t, 512, y, 512, kvt, 4096, 512,
                              b & 31, b >> 5, 1.f, smem);
}

// build_u: grid (16,8); Ut tile (s,h) = scale * V_rows @ K_rows^T, K=256.
__global__ __launch_bounds__(256)
void build_u(const short* __restrict__ kvt, const float* __restrict__ cw,
             short* __restrict__ Ut) {
    __shared__ char smem[65536];
    const int s = blockIdx.x, h = blockIdx.y;
    const float scale = cw[h] * (0.08838834764831845f / 256.0f);
    gemm_tile<2, false, false>(
        kvt + (size_t)(1024 + h * 128) * 4096 + s * 256, 4096,   // V
        kvt + (size_t)(h * 128) * 4096 + s * 256, 4096,          // K
        Ut + (size_t)(s * 128) * 1024 + h * 128, 1024, 256,
        0, 0, scale, smem);
}

// build_m: M[2048,512] = Ut @ W1-rows (Bt = W1 fp32 [512,1024]), K=1024.
// grid (4,16) = 64 blocks.
__global__ __launch_bounds__(256)
void build_m(const short* __restrict__ Ut, const float* __restrict__ W1,
             short* __restrict__ M) {
    __shared__ char smem[65536];
    gemm_tile<1, false, true>(Ut, 1024, W1, 1024, M, 512, 1024,
                              blockIdx.x, blockIdx.y, 1.f, smem);
}

// gemm_out: out[4096,2048] = bf16(x) @ M^T, K=512. 512 blocks, XCD-swizzled.
__global__ __launch_bounds__(256)
void gemm_out(const float* __restrict__ x, const short* __restrict__ M,
              float* __restrict__ out) {
    __shared__ char smem[65536];
    const int b = (blockIdx.x & 7) * 64 + (blockIdx.x >> 3);
    gemm_tile<0, true, false>(x, 512, M, 512, out, 2048, 512,
                              b & 15, b >> 4, 1.f, smem);
}

extern "C" void kernel_launch(void* const* d_in, const int* in_sizes, int n_in,
                              void* d_out, int out_size, void* d_ws, size_t ws_size,
                              hipStream_t stream) {
    const float* x  = (const float*)d_in[0];  // [4096, 512]
    const float* y  = (const float*)d_in[1];  // [4096, 512]
    const float* W1 = (const float*)d_in[2];  // [512, 1024]
    const float* W2 = (const float*)d_in[3];
    const float* W3 = (const float*)d_in[4];
    const float* cw = (const float*)d_in[5];  // [8]
    float* out = (float*)d_out;               // [4096, 16, 128]

    short* w23t = (short*)d_ws;                       // 2048*512 (transposed)
    short* kvt  = w23t + (size_t)2048 * 512;          // 2048*4096
    short* Ut   = kvt  + (size_t)2048 * 4096;         // 2048*1024
    short* M    = Ut   + (size_t)2048 * 1024;         // 2048*512

    prep<<<1024, 256, 0, stream>>>(W2, W3, w23t);
    stage_kv<<<512, 256, 0, stream>>>(y, w23t, kvt);
    build_u<<<dim3(16, 8), 256, 0, stream>>>(kvt, cw, Ut);
    build_m<<<dim3(4, 16), 256, 0, stream>>>(Ut, W1, M);
    gemm_out<<<512, 256, 0, stream>>>(x, M, out);
}

// Round 11
// 129.086 us; speedup vs baseline: 4.7108x; 1.2099x over previous
//
#include <hip/hip_runtime.h>
#include <stdint.h>
#include <stddef.h>

// ---------------------------------------------------------------------------
// cseft reassociated, W1 folded into U. 5 launches. FINAL (R6-verified
// structure, 129.4us):
//   1. prep:  xb=bf16(x), yb=bf16(y), w1b=bf16(W1) [512,1024],
//             w23t=bf16([W2|W3]^T) [2048,512]
//   2. stage_kv: kvt[2048,4096] = w23t @ yb^T
//   3. build_u:  Ut[s*128+d][h*128+dp] = cw[h]*sc * V_s @ K_s^T (K=256)
//   4. build_m:  M[2048,512] = Ut @ W1  (K=1024, bf16)
//   5. gemm_out: out[4096,2048] = xb @ M^T  (K=512, fp32)
// N=4096 K=512 H=8 Dh=128 nItem=256 nSet=16 hardcoded.
//
// gemm_tile: BK=64 (128B cache-line staging), dbuf 2x32KB, 1 barrier/step,
// T2 both-sides XOR swizzle (linear LDS dest + pre-swizzled global source +
// XOR'd ds_read — rule #21), T1 bijective XCD swizzle on 512- and 128-block
// grids.
//
// SESSION LEDGER (all measured, do not reopen):
// - R10 conversion-folding into consumers (T14 reg-staging): 156.2 (-27 vs
//   R6). Reg-staging f32 operands doubles staged bytes + puts cvt/ds_write
//   on the critical path. Pre-converted bf16 + global_load_lds wins.
// - Fusion arc: R3 coop never ran under graph capture; R5 sw-barrier
//   replay-diverged (stale per-XCD L2); R8 acquire-per-poll 530us; R9
//   relaxed+wbl2/inv 211us (buffer_inv wipes whole L2 -> full refetch).
//   Kernel boundaries are the efficient coherence mechanism.
// - R7 qb-dataflow: 132.2. R4 depth-2 counted vmcnt: null. R1 build_m-only
//   split: 147.5.
// Accounting: ~90us harness fill floor + ~10us launch gaps + ~30us phases.
// ---------------------------------------------------------------------------

typedef short short8 __attribute__((ext_vector_type(8)));
typedef float f32x4 __attribute__((ext_vector_type(4)));

#define AS1 __attribute__((address_space(1)))
#define AS3 __attribute__((address_space(3)))

__device__ __forceinline__ void gl_lds16(const void* g, void* l) {
    __builtin_amdgcn_global_load_lds((AS1 void*)(uintptr_t)g, (AS3 void*)l, 16, 0, 0);
}

__device__ __forceinline__ short f2bf(float f) {
    union { float f; unsigned u; } v; v.f = f;
    unsigned r = v.u + 0x7FFFu + ((v.u >> 16) & 1u);
    return (short)(r >> 16);
}

// --- prep: 0..1023 x->xb, 1024..2047 y->yb, 2048..3071 W2/W3->w23t (T),
//     3072..3327 W1->w1b (straight bf16 convert). 3328 blocks x 256 thr.
__global__ __launch_bounds__(256)
void prep(const float* __restrict__ x, const float* __restrict__ y,
          const float* __restrict__ W1, const float* __restrict__ W2,
          const float* __restrict__ W3, short* __restrict__ xb,
          short* __restrict__ yb, short* __restrict__ w1b,
          short* __restrict__ w23t) {
    const int b = blockIdx.x, tid = threadIdx.x;
    if (b < 2048) {
        const float* in = (b < 1024) ? x : y;
        short* o = (b < 1024) ? xb : yb;
        const int i = (b & 1023) * 256 + tid;
        const float4* p = (const float4*)in + (size_t)i * 2;
        float4 a = p[0], c4 = p[1];
        short8 s8;
        s8[0] = f2bf(a.x);  s8[1] = f2bf(a.y);
        s8[2] = f2bf(a.z);  s8[3] = f2bf(a.w);
        s8[4] = f2bf(c4.x); s8[5] = f2bf(c4.y);
        s8[6] = f2bf(c4.z); s8[7] = f2bf(c4.w);
        *((short8*)o + i) = s8;
        return;
    }
    if (b >= 3072) {
        const int i = (b - 3072) * 256 + tid;
        const float4* p = (const float4*)W1 + (size_t)i * 2;
        float4 a = p[0], c4 = p[1];
        short8 s8;
        s8[0] = f2bf(a.x);  s8[1] = f2bf(a.y);
        s8[2] = f2bf(a.z);  s8[3] = f2bf(a.w);
        s8[4] = f2bf(c4.x); s8[5] = f2bf(c4.y);
        s8[6] = f2bf(c4.z); s8[7] = f2bf(c4.w);
        *((short8*)w1b + i) = s8;
        return;
    }
    __shared__ float t[32][33];
    const int b2 = b - 2048;                     // 0..1023
    const int z = b2 >> 9;                       // 0: W2, 1: W3
    const float* W = z ? W3 : W2;
    short* Wt = w23t + (size_t)z * 1024 * 512;
    const int b3 = b2 & 511;
    const int bx = (b3 & 31) * 32, by = (b3 >> 5) * 32;
    const int tx = tid & 31, ty = tid >> 5;
    #pragma unroll
    for (int j = 0; j < 4; ++j)
        t[ty + j * 8][tx] = W[(size_t)(by + ty + j * 8) * 1024 + bx + tx];
    __syncthreads();
    #pragma unroll
    for (int j = 0; j < 4; ++j)
        Wt[(size_t)(bx + ty + j * 8) * 512 + by + tx] = f2bf(t[tx][ty + j * 8]);
}

// --- generic MFMA tile: C[128x128] = A[.,K] * Bt[.,K]^T --------------------
// 4 waves 2x2; OUTMODE: 0 = f32 store, 1 = bf16 store, 2 = bf16*scale.
// BK=64, dbuf 2x32KB, 1 __syncthreads per step, XOR-swizzled LDS (T2).
// Buffer layout: [A 128 rows x 128B][B 128 rows x 128B]; LDS holds global
// chunk (row, c^(row&7)) at physical (row, c) -> read addr XORs the same.
template <int OUTMODE>
__device__ __forceinline__
void gemm_tile(const short* __restrict__ A, int lda,
               const short* __restrict__ Bt, int ldb,
               void* __restrict__ Cout, int ldc, int K,
               int bx, int by, float scale, char* smem) {
    const int tid = threadIdx.x;
    const int wave = tid >> 6, lane = tid & 63;
    const int quad = lane >> 4, ml = lane & 15;
    const int m0 = by * 128, n0 = bx * 128;
    const int wm0 = (wave >> 1) * 64, wn0 = (wave & 1) * 64;
    const int rl = lane >> 3;            // row within an 8-row group (0..7)
    const int ch = lane & 7;             // 16B chunk within 128B row (0..7)
    const int sch = ch ^ rl;             // source-swizzled chunk (involution)

    f32x4 acc[4][4];
    #pragma unroll
    for (int i = 0; i < 4; ++i)
        #pragma unroll
        for (int j = 0; j < 4; ++j) {
            acc[i][j][0] = 0.f; acc[i][j][1] = 0.f;
            acc[i][j][2] = 0.f; acc[i][j][3] = 0.f;
        }

    // Stage A[128x64] + B[128x64] bf16. 8 gl_lds per thread; each instr
    // covers 8 rows x 128B (full cache lines). r&7 == rl so global chunk
    // ch^rl lands at physical chunk ch -> read side XORs row&7.
    auto STAGE = [&](char* sbuf, int kt) {
        #pragma unroll
        for (int j = 0; j < 4; ++j) {
            const int r = (wave * 4 + j) * 8 + rl;
            gl_lds16(A + (size_t)(m0 + r) * lda + kt + sch * 8,
                     sbuf + (wave * 4 + j) * 1024 + lane * 16);
        }
        #pragma unroll
        for (int j = 0; j < 4; ++j) {
            const int r = (wave * 4 + j) * 8 + rl;
            gl_lds16(Bt + (size_t)(n0 + r) * ldb + kt + sch * 8,
                     sbuf + 16384 + (wave * 4 + j) * 1024 + lane * 16);
        }
    };

    const int nt = K >> 6;               // >= 4 at every call site
    STAGE(smem, 0);
    __syncthreads();                     // drain vmcnt(0): buf0 ready

    for (int t = 0; t < nt; ++t) {
        char* sbuf = smem + (t & 1) * 32768;
        if (t + 1 < nt)
            STAGE(smem + ((t + 1) & 1) * 32768, (t + 1) * 64);  // prefetch

        const short* sA = (const short*)sbuf;
        const short* sB = (const short*)(sbuf + 16384);
        #pragma unroll
        for (int kk = 0; kk < 2; ++kk) {
            short8 af[4], bfr[4];
            #pragma unroll
            for (int mt = 0; mt < 4; ++mt) {
                const int row = wm0 + mt * 16 + ml;
                af[mt] = *(const short8*)(sA + row * 64 +
                                          (((kk << 2) + quad) ^ (row & 7)) * 8);
            }
            #pragma unroll
            for (int nt2 = 0; nt2 < 4; ++nt2) {
                const int row = wn0 + nt2 * 16 + ml;
                bfr[nt2] = *(const short8*)(sB + row * 64 +
                                            (((kk << 2) + quad) ^ (row & 7)) * 8);
            }
            #pragma unroll
            for (int mt = 0; mt < 4; ++mt)
                #pragma unroll
                for (int nt2 = 0; nt2 < 4; ++nt2)
                    acc[mt][nt2] = __builtin_amdgcn_mfma_f32_16x16x32_bf16(
                        af[mt], bfr[nt2], acc[mt][nt2], 0, 0, 0);
        }
        __syncthreads();  // next buf ready; all waves done reading sbuf
    }

    // C/D layout: col = lane&15, row = quad*4 + reg
    #pragma unroll
    for (int mt = 0; mt < 4; ++mt)
        #pragma unroll
        for (int nt2 = 0; nt2 < 4; ++nt2) {
            const int col = n0 + wn0 + nt2 * 16 + ml;
            #pragma unroll
            for (int r = 0; r < 4; ++r) {
                const int row = m0 + wm0 + mt * 16 + quad * 4 + r;
                float v = acc[mt][nt2][r];
                if (OUTMODE == 2) v *= scale;
                if (OUTMODE == 0)
                    ((float*)Cout)[(size_t)row * ldc + col] = v;
                else
                    ((short*)Cout)[(size_t)row * ldc + col] = f2bf(v);
            }
        }
}

// stage_kv: kvt[2048,4096] = w23t @ yb^T : m-tiles 16, n-tiles 32. 512 blocks.
__global__ __launch_bounds__(256)
void stage_kv(const short* __restrict__ yb, const short* __restrict__ w23t,
              short* __restrict__ kvt) {
    __shared__ char smem[65536];
    const int b = (blockIdx.x & 7) * 64 + (blockIdx.x >> 3);   // T1 bijective
    gemm_tile<1>(w23t, 512, yb, 512, kvt, 4096, 512,
                 b & 31, b >> 5, 1.f, smem);
}

// build_u: 128 blocks (XCD-swizzled); Ut tile (s,h) = scale * V_s @ K_s^T.
__global__ __launch_bounds__(256)
void build_u(const short* __restrict__ kvt, const float* __restrict__ cw,
             short* __restrict__ Ut) {
    __shared__ char smem[65536];
    const int b = (blockIdx.x & 7) * 16 + (blockIdx.x >> 3);   // 128 % 8 == 0
    const int s = b & 15, h = b >> 4;
    const float scale = cw[h] * (0.08838834764831845f / 256.0f);
    gemm_tile<2>(kvt + (size_t)(1024 + h * 128) * 4096 + s * 256, 4096,  // V
                 kvt + (size_t)(h * 128) * 4096 + s * 256, 4096,         // K
                 Ut + (size_t)(s * 128) * 1024 + h * 128, 1024, 256,
                 0, 0, scale, smem);
}

// build_m: M[2048,512] = Ut @ W1 (Bt = w1b row-major [512,1024]), K=1024.
// grid (4,16) = 64 blocks.
__global__ __launch_bounds__(256)
void build_m(const short* __restrict__ Ut, const short* __restrict__ w1b,
             short* __restrict__ M) {
    __shared__ char smem[65536];
    gemm_tile<1>(Ut, 1024, w1b, 1024, M, 512, 1024,
                 blockIdx.x, blockIdx.y, 1.f, smem);
}

// out[4096,2048] = xb @ M^T, fp32, K=512. 512 blocks (XCD-swizzled).
__global__ __launch_bounds__(256)
void gemm_out(const short* __restrict__ xb, const short* __restrict__ M,
              float* __restrict__ out) {
    __shared__ char smem[65536];
    const int b = (blockIdx.x & 7) * 64 + (blockIdx.x >> 3);
    gemm_tile<0>(xb, 512, M, 512, out, 2048, 512,
                 b & 15, b >> 4, 1.f, smem);
}

extern "C" void kernel_launch(void* const* d_in, const int* in_sizes, int n_in,
                              void* d_out, int out_size, void* d_ws, size_t ws_size,
                              hipStream_t stream) {
    const float* x  = (const float*)d_in[0];  // [4096, 512]
    const float* y  = (const float*)d_in[1];  // [4096, 512]
    const float* W1 = (const float*)d_in[2];  // [512, 1024]
    const float* W2 = (const float*)d_in[3];
    const float* W3 = (const float*)d_in[4];
    const float* cw = (const float*)d_in[5];  // [8]
    float* out = (float*)d_out;               // [4096, 16, 128]

    short* xb   = (short*)d_ws;                       // 4096*512
    short* yb   = xb   + (size_t)4096 * 512;          // 4096*512
    short* w23t = yb   + (size_t)4096 * 512;          // 2048*512 (transposed)
    short* w1b  = w23t + (size_t)2048 * 512;          // 512*1024 (row-major)
    short* kvt  = w1b  + (size_t)512 * 1024;          // 2048*4096
    short* Ut   = kvt  + (size_t)2048 * 4096;         // 2048*1024
    short* M    = Ut   + (size_t)2048 * 1024;         // 2048*512

    prep<<<3328, 256, 0, stream>>>(x, y, W1, W2, W3, xb, yb, w1b, w23t);
    stage_kv<<<512, 256, 0, stream>>>(yb, w23t, kvt);
    build_u<<<128, 256, 0, stream>>>(kvt, cw, Ut);
    build_m<<<dim3(4, 16), 256, 0, stream>>>(Ut, w1b, M);
    gemm_out<<<512, 256, 0, stream>>>(xb, M, out);
}